// Round 1
// baseline (1292.036 us; speedup 1.0000x reference)
//
#include <hip/hip_runtime.h>
#include <math.h>

#define NB 256       // batch
#define HT 17
#define WT 17
#define HI 384
#define WI 384
#define LH 368
#define LW 368
#define NTEMPL 289   // HT*WT
#define TPAD 20      // padded template row width (float4-friendly, zeros in 17..19)
#define TILE 32      // output tile (32x32)
#define NTX 12       // tiles per dimension (12*32=384 >= 368)
#define NTILES 144   // 12*12
#define ITILE 48     // input tile rows/cols needed (32+17-1)
#define IPITCH 52    // LDS pitch (multiple of 4 for float4 alignment)
#define TEMP_INV 25.0f   // 1/0.04
#define EPSV 1e-6f

// ---------------- kernel 1: per-batch template normalization ----------------
__global__ __launch_bounds__(256) void tmpl_norm_kernel(
    const float* __restrict__ piece, float* __restrict__ tn) {
    int b = blockIdx.x;
    const float* x = piece + b * NTEMPL;
    int tid = threadIdx.x;
    int wid = tid >> 6, lane = tid & 63;

    float v0 = (tid < NTEMPL) ? x[tid] : 0.f;
    float v1 = (tid + 256 < NTEMPL) ? x[tid + 256] : 0.f;

    __shared__ float sred[4];
    float s = v0 + v1;
    #pragma unroll
    for (int o = 32; o > 0; o >>= 1) s += __shfl_down(s, o, 64);
    if (lane == 0) sred[wid] = s;
    __syncthreads();
    float mean = (sred[0] + sred[1] + sred[2] + sred[3]) * (1.0f / NTEMPL);

    float d0 = (tid < NTEMPL) ? (v0 - mean) : 0.f;
    float d1 = (tid + 256 < NTEMPL) ? (v1 - mean) : 0.f;
    float q = d0 * d0 + d1 * d1;
    __syncthreads();
    #pragma unroll
    for (int o = 32; o > 0; o >>= 1) q += __shfl_down(q, o, 64);
    if (lane == 0) sred[wid] = q;
    __syncthreads();
    float var = (sred[0] + sred[1] + sred[2] + sred[3]) * (1.0f / (NTEMPL - 1));
    float stdv = sqrtf(var);
    if (stdv < EPSV) stdv = EPSV;
    float inv = 1.0f / stdv;

    float* o = tn + b * (HT * TPAD);
    for (int sIdx = tid; sIdx < HT * TPAD; sIdx += 256) {
        int i = sIdx / TPAD, j = sIdx % TPAD;
        o[sIdx] = (j < WT) ? (x[i * WT + j] - mean) * inv : 0.f;
    }
}

// ---------------- kernel 2: correlation + per-tile softmax partials ----------------
__global__ __launch_bounds__(256) void corr_kernel(
    const float* __restrict__ bgg, const float* __restrict__ tn,
    float* __restrict__ partials) {
    int blk = blockIdx.x;
    int b = blk / NTILES;
    int t = blk % NTILES;
    int ty0 = (t / NTX) * TILE;
    int tx0 = (t % NTX) * TILE;
    const float* img = bgg + (size_t)b * HI * WI;

    __shared__ float bg[ITILE][IPITCH];   // 48x52 input tile (0-padded OOB)
    __shared__ float tpl[HT * TPAD];      // zero-padded template
    __shared__ float c1[TILE][IPITCH];    // vertical sums
    __shared__ float c2[TILE][IPITCH];    // vertical sums of squares
    __shared__ float redm[4], redl[4], redy[4], redx[4];

    int tid = threadIdx.x;
    int wid = tid >> 6, lane = tid & 63;

    // template -> LDS
    for (int sIdx = tid; sIdx < HT * TPAD; sIdx += 256)
        tpl[sIdx] = tn[b * HT * TPAD + sIdx];
    // background tile -> LDS (0 outside image; cols 48..51 only hit zero template taps)
    for (int l = tid; l < ITILE * IPITCH; l += 256) {
        int r = l / IPITCH, c = l % IPITCH;
        int iy = ty0 + r, ix = tx0 + c;
        float v = 0.f;
        if (iy < HI && ix < WI) v = img[iy * WI + ix];
        bg[r][c] = v;
    }
    __syncthreads();

    // separable vertical sums (17-row column sums) for s1/s2
    for (int l = tid; l < TILE * ITILE; l += 256) {  // 1536 entries
        int r = l / ITILE, c = l % ITILE;
        float s = 0.f, s2 = 0.f;
        #pragma unroll
        for (int i = 0; i < HT; ++i) { float v = bg[r + i][c]; s += v; s2 = fmaf(v, v, s2); }
        c1[r][c] = s; c2[r][c] = s2;
    }
    __syncthreads();

    // main: each thread -> 4 consecutive outputs in x
    int ty = tid >> 3;         // 0..31
    int xb = (tid & 7) * 4;    // 0..28
    float acc0 = 0.f, acc1 = 0.f, acc2 = 0.f, acc3 = 0.f;
    #pragma unroll
    for (int i = 0; i < HT; ++i) {
        float bb[24], tt[TPAD];
        const float4* br = (const float4*)&bg[ty + i][xb];   // 16B aligned: pitch 52, xb%4==0
        #pragma unroll
        for (int q = 0; q < 6; ++q) ((float4*)bb)[q] = br[q];
        const float4* tr = (const float4*)&tpl[i * TPAD];
        #pragma unroll
        for (int q = 0; q < 5; ++q) ((float4*)tt)[q] = tr[q];
        #pragma unroll
        for (int j = 0; j < TPAD; ++j) {
            float tv = tt[j];
            acc0 = fmaf(tv, bb[j],     acc0);
            acc1 = fmaf(tv, bb[j + 1], acc1);
            acc2 = fmaf(tv, bb[j + 2], acc2);
            acc3 = fmaf(tv, bb[j + 3], acc3);
        }
    }

    // sliding window stats via column sums + running update
    float s1 = 0.f, s2 = 0.f;
    #pragma unroll
    for (int j = 0; j < HT; ++j) { s1 += c1[ty][xb + j]; s2 += c2[ty][xb + j]; }
    float accs[4] = {acc0, acc1, acc2, acc3};
    float corr[4];
    const float invn = 1.0f / NTEMPL;
    #pragma unroll
    for (int k = 0; k < 4; ++k) {
        float mu = s1 * invn;
        float var = s2 * invn - mu * mu;
        if (var < EPSV) var = EPSV;
        corr[k] = accs[k] / sqrtf(var);
        if (k < 3) {
            s1 += c1[ty][xb + k + HT] - c1[ty][xb + k];
            s2 += c2[ty][xb + k + HT] - c2[ty][xb + k];
        }
    }

    int oy = ty0 + ty;
    bool rowok = oy < LH;
    float m = -INFINITY;
    #pragma unroll
    for (int k = 0; k < 4; ++k) {
        int ox = tx0 + xb + k;
        if (rowok && ox < LW) m = fmaxf(m, corr[k]);
        else corr[k] = -INFINITY;
    }

    // block max
    float mm = m;
    #pragma unroll
    for (int o = 32; o > 0; o >>= 1) mm = fmaxf(mm, __shfl_down(mm, o, 64));
    if (lane == 0) redm[wid] = mm;
    __syncthreads();
    float M = fmaxf(fmaxf(redm[0], redm[1]), fmaxf(redm[2], redm[3]));

    // partial softmax sums relative to tile max
    float l = 0.f, sy = 0.f, sx = 0.f;
    #pragma unroll
    for (int k = 0; k < 4; ++k) {
        float e = (corr[k] == -INFINITY) ? 0.f : __expf((corr[k] - M) * TEMP_INV);
        l += e;
        sy = fmaf(e, (float)oy, sy);
        sx = fmaf(e, (float)(tx0 + xb + k), sx);
    }
    #pragma unroll
    for (int o = 32; o > 0; o >>= 1) {
        l  += __shfl_down(l, o, 64);
        sy += __shfl_down(sy, o, 64);
        sx += __shfl_down(sx, o, 64);
    }
    if (lane == 0) { redl[wid] = l; redy[wid] = sy; redx[wid] = sx; }
    __syncthreads();
    if (tid == 0) {
        float* p = partials + (size_t)blk * 4;
        p[0] = M;
        p[1] = redl[0] + redl[1] + redl[2] + redl[3];
        p[2] = redy[0] + redy[1] + redy[2] + redy[3];
        p[3] = redx[0] + redx[1] + redx[2] + redx[3];
    }
}

// ---------------- kernel 3: per-batch merge of tile partials ----------------
__global__ __launch_bounds__(256) void reduce_kernel(
    const float* __restrict__ partials, float* __restrict__ out) {
    int b = blockIdx.x;
    int tid = threadIdx.x;
    int wid = tid >> 6, lane = tid & 63;

    float m = -INFINITY, l = 0.f, sy = 0.f, sx = 0.f;
    if (tid < NTILES) {
        const float* p = partials + (size_t)(b * NTILES + tid) * 4;
        m = p[0]; l = p[1]; sy = p[2]; sx = p[3];
    }
    __shared__ float rm[4], rl[4], ry[4], rx[4];
    float mm = m;
    #pragma unroll
    for (int o = 32; o > 0; o >>= 1) mm = fmaxf(mm, __shfl_down(mm, o, 64));
    if (lane == 0) rm[wid] = mm;
    __syncthreads();
    float M = fmaxf(fmaxf(rm[0], rm[1]), fmaxf(rm[2], rm[3]));

    float sc = (m == -INFINITY) ? 0.f : __expf((m - M) * TEMP_INV);
    l *= sc; sy *= sc; sx *= sc;
    #pragma unroll
    for (int o = 32; o > 0; o >>= 1) {
        l  += __shfl_down(l, o, 64);
        sy += __shfl_down(sy, o, 64);
        sx += __shfl_down(sx, o, 64);
    }
    if (lane == 0) { rl[wid] = l; ry[wid] = sy; rx[wid] = sx; }
    __syncthreads();
    if (tid == 0) {
        float L  = rl[0] + rl[1] + rl[2] + rl[3];
        float SY = ry[0] + ry[1] + ry[2] + ry[3];
        float SX = rx[0] + rx[1] + rx[2] + rx[3];
        out[b * 2 + 0] = SX / L - 183.5f;   // offset_x, (Lw-1)/2 = 183.5
        out[b * 2 + 1] = SY / L - 183.5f;   // offset_y
        out[2 * NB + b] = M;                // max_corr
    }
}

extern "C" void kernel_launch(void* const* d_in, const int* in_sizes, int n_in,
                              void* d_out, int out_size, void* d_ws, size_t ws_size,
                              hipStream_t stream) {
    const float* piece = (const float*)d_in[0];   // [256,1,17,17]
    const float* bgg   = (const float*)d_in[1];   // [256,1,384,384]
    float* out = (float*)d_out;                   // 512 offsets + 256 max_corr

    float* tn = (float*)d_ws;                            // 256 * 340 floats
    float* partials = tn + NB * HT * TPAD;               // 256*144*4 floats

    tmpl_norm_kernel<<<NB, 256, 0, stream>>>(piece, tn);
    corr_kernel<<<NB * NTILES, 256, 0, stream>>>(bgg, tn, partials);
    reduce_kernel<<<NB, 256, 0, stream>>>(partials, out);
}

// Round 2
// 548.637 us; speedup vs baseline: 2.3550x; 2.3550x over previous
//
#include <hip/hip_runtime.h>
#include <math.h>

#define NB 256       // batch
#define HT 17
#define WT 17
#define HI 384
#define WI 384
#define LH 368
#define LW 368
#define NTEMPL 289   // HT*WT
#define TPAD 20      // padded template row width (float4-friendly)
#define TY 32        // output tile rows per block
#define TX 128       // output tile cols per block
#define NTXT 3       // x tiles (3*128 = 384)
#define NTYT 12      // y tiles (12*32 = 384)
#define NTILES 36    // tiles per batch
#define BR 48        // bg tile rows (TY + 16)
#define BP 144       // bg/c1/c2 pitch = TX + 16 (multiple of 4)
#define TEMP_INV 25.0f
#define EPSV 1e-6f

// ---------------- kernel 1: per-batch template normalization ----------------
__global__ __launch_bounds__(256) void tmpl_norm_kernel(
    const float* __restrict__ piece, float* __restrict__ tn) {
    int b = blockIdx.x;
    const float* x = piece + b * NTEMPL;
    int tid = threadIdx.x;
    int wid = tid >> 6, lane = tid & 63;

    float v0 = (tid < NTEMPL) ? x[tid] : 0.f;
    float v1 = (tid + 256 < NTEMPL) ? x[tid + 256] : 0.f;

    __shared__ float sred[4];
    float s = v0 + v1;
    #pragma unroll
    for (int o = 32; o > 0; o >>= 1) s += __shfl_down(s, o, 64);
    if (lane == 0) sred[wid] = s;
    __syncthreads();
    float mean = (sred[0] + sred[1] + sred[2] + sred[3]) * (1.0f / NTEMPL);

    float d0 = (tid < NTEMPL) ? (v0 - mean) : 0.f;
    float d1 = (tid + 256 < NTEMPL) ? (v1 - mean) : 0.f;
    float q = d0 * d0 + d1 * d1;
    __syncthreads();
    #pragma unroll
    for (int o = 32; o > 0; o >>= 1) q += __shfl_down(q, o, 64);
    if (lane == 0) sred[wid] = q;
    __syncthreads();
    float var = (sred[0] + sred[1] + sred[2] + sred[3]) * (1.0f / (NTEMPL - 1));
    float stdv = sqrtf(var);
    if (stdv < EPSV) stdv = EPSV;
    float inv = 1.0f / stdv;

    float* o = tn + b * (HT * TPAD);
    for (int sIdx = tid; sIdx < HT * TPAD; sIdx += 256) {
        int i = sIdx / TPAD, j = sIdx % TPAD;
        o[sIdx] = (j < WT) ? (x[i * WT + j] - mean) * inv : 0.f;
    }
}

// ---------------- main-loop step: compile-time slot rotation ----------------
// At step i, bbf slots hold bg rows ty4+i .. ty4+i+3 (slot = row & 3).
// Template row i+1 is software-pipelined into ttf[(C+1)&1].
template<int C, bool LAST>
__device__ __forceinline__ void corr_step(
    int ib, int ty4, int xb,
    const float* __restrict__ tp,
    const float (*__restrict__ bg)[BP],
    float (&bbf)[4][TPAD], float (&ttf)[2][TPAD], float (&acc)[4][4])
{
    const int i = ib + C;
    if (!LAST) {
        const float4* tq = (const float4*)(tp + (i + 1) * TPAD);
        #pragma unroll
        for (int q = 0; q < 5; ++q) ((float4*)ttf[(C + 1) & 1])[q] = tq[q];
    }
    {   // load new bg row (ty4+i+3) into slot (C+3)&3 — consumed late (ry=3)
        const float4* br = (const float4*)&bg[ty4 + i + 3][xb];
        #pragma unroll
        for (int q = 0; q < 5; ++q) ((float4*)bbf[(C + 3) & 3])[q] = br[q];
    }
    const float* tc = ttf[C & 1];
    #pragma unroll
    for (int ry = 0; ry < 4; ++ry) {
        const float* rw = bbf[(C + ry) & 3];
        #pragma unroll
        for (int j = 0; j < 17; ++j) {
            const float tv = tc[j];
            #pragma unroll
            for (int k = 0; k < 4; ++k)
                acc[ry][k] = fmaf(tv, rw[j + k], acc[ry][k]);
        }
    }
}

// ---------------- kernel 2: correlation + per-tile softmax partials ----------------
__global__ __launch_bounds__(256, 2) void corr_kernel(
    const float* __restrict__ bgg, const float* __restrict__ tn,
    float* __restrict__ partials) {
    int blk = blockIdx.x;
    int b = blk / NTILES;
    int t = blk % NTILES;
    int ty0 = (t / NTXT) * TY;
    int tx0 = (t % NTXT) * TX;
    const float* img = bgg + (size_t)b * HI * WI;
    const float* tp  = tn + b * (HT * TPAD);

    __shared__ float bg[BR][BP];   // 27648 B
    __shared__ float c1[TY][BP];   // 18432 B  (17-row column sums)
    __shared__ float c2[TY][BP];   // 18432 B  (17-row column sums of squares)
    __shared__ float redm[4], redl[4], redy[4], redx[4];

    int tid = threadIdx.x;
    int wid = tid >> 6, lane = tid & 63;

    // ---- stage bg tile (zero-filled OOB); rows/cols are 4-aligned vs 384 ----
    for (int l = tid; l < BR * (BP / 4); l += 256) {
        int r = l / (BP / 4), c = (l % (BP / 4)) * 4;
        int iy = ty0 + r, ix = tx0 + c;
        float4 v = make_float4(0.f, 0.f, 0.f, 0.f);
        if (iy < HI && ix < WI) v = *(const float4*)(img + iy * WI + ix);
        *(float4*)&bg[r][c] = v;
    }
    __syncthreads();

    // ---- incremental 17-row column sums (stride-1 lanes: conflict-free) ----
    for (int tsk = tid; tsk < 2 * BP; tsk += 256) {
        int cc = tsk % BP, r0 = (tsk / BP) * 16;
        float s = 0.f, s2 = 0.f;
        #pragma unroll
        for (int i2 = 0; i2 < HT; ++i2) { float v = bg[r0 + i2][cc]; s += v; s2 = fmaf(v, v, s2); }
        c1[r0][cc] = s; c2[r0][cc] = s2;
        for (int r = r0 + 1; r < r0 + 16; ++r) {
            float vn = bg[r + 16][cc], vo = bg[r - 1][cc];
            s += vn - vo; s2 += vn * vn - vo * vo;
            c1[r][cc] = s; c2[r][cc] = s2;
        }
    }
    // no barrier needed yet: main loop only reads bg; c1/c2 guarded by the
    // barrier after the (long) main loop.

    // ---- main loop: 4x4 micro-tile, rolling 4-row register window ----
    int ty4 = (tid >> 5) * 4;    // 0..28
    int xb  = (tid & 31) * 4;    // 0..124
    float bbf[4][TPAD];
    float ttf[2][TPAD];
    float acc[4][4] = {};

    #pragma unroll
    for (int m = 0; m < 3; ++m) {
        const float4* br = (const float4*)&bg[ty4 + m][xb];
        #pragma unroll
        for (int q = 0; q < 5; ++q) ((float4*)bbf[m])[q] = br[q];
    }
    {
        const float4* t0 = (const float4*)tp;
        #pragma unroll
        for (int q = 0; q < 5; ++q) ((float4*)ttf[0])[q] = t0[q];
    }

    for (int ib = 0; ib < 16; ib += 4) {
        corr_step<0, false>(ib, ty4, xb, tp, bg, bbf, ttf, acc);
        corr_step<1, false>(ib, ty4, xb, tp, bg, bbf, ttf, acc);
        corr_step<2, false>(ib, ty4, xb, tp, bg, bbf, ttf, acc);
        corr_step<3, false>(ib, ty4, xb, tp, bg, bbf, ttf, acc);
    }
    corr_step<0, true>(16, ty4, xb, tp, bg, bbf, ttf, acc);

    __syncthreads();   // c1/c2 ready (written long ago)

    // ---- window stats via float4 reads of column sums + sliding update ----
    const float invn = 1.0f / NTEMPL;
    float corr[4][4];
    float m = -INFINITY;
    #pragma unroll
    for (int ry = 0; ry < 4; ++ry) {
        float cc1f[TPAD], cc2f[TPAD];
        const float4* a1 = (const float4*)&c1[ty4 + ry][xb];
        const float4* a2 = (const float4*)&c2[ty4 + ry][xb];
        #pragma unroll
        for (int q = 0; q < 5; ++q) { ((float4*)cc1f)[q] = a1[q]; ((float4*)cc2f)[q] = a2[q]; }
        float s1 = 0.f, s2 = 0.f;
        #pragma unroll
        for (int j = 0; j < HT; ++j) { s1 += cc1f[j]; s2 += cc2f[j]; }
        int oy = ty0 + ty4 + ry;
        #pragma unroll
        for (int k = 0; k < 4; ++k) {
            float mu = s1 * invn;
            float var = s2 * invn - mu * mu;
            if (var < EPSV) var = EPSV;
            float cv = acc[ry][k] / sqrtf(var);
            int ox = tx0 + xb + k;
            if (oy < LH && ox < LW) m = fmaxf(m, cv);
            else cv = -INFINITY;
            corr[ry][k] = cv;
            if (k < 3) {
                s1 += cc1f[k + HT] - cc1f[k];
                s2 += cc2f[k + HT] - cc2f[k];
            }
        }
    }

    // ---- block max ----
    float mm = m;
    #pragma unroll
    for (int o = 32; o > 0; o >>= 1) mm = fmaxf(mm, __shfl_down(mm, o, 64));
    if (lane == 0) redm[wid] = mm;
    __syncthreads();
    float M = fmaxf(fmaxf(redm[0], redm[1]), fmaxf(redm[2], redm[3]));

    // ---- partial softmax sums relative to tile max ----
    float l = 0.f, sy = 0.f, sx = 0.f;
    #pragma unroll
    for (int ry = 0; ry < 4; ++ry) {
        int oy = ty0 + ty4 + ry;
        #pragma unroll
        for (int k = 0; k < 4; ++k) {
            float cv = corr[ry][k];
            float e = (cv == -INFINITY) ? 0.f : __expf((cv - M) * TEMP_INV);
            l += e;
            sy = fmaf(e, (float)oy, sy);
            sx = fmaf(e, (float)(tx0 + xb + k), sx);
        }
    }
    #pragma unroll
    for (int o = 32; o > 0; o >>= 1) {
        l  += __shfl_down(l, o, 64);
        sy += __shfl_down(sy, o, 64);
        sx += __shfl_down(sx, o, 64);
    }
    if (lane == 0) { redl[wid] = l; redy[wid] = sy; redx[wid] = sx; }
    __syncthreads();
    if (tid == 0) {
        float* p = partials + (size_t)blk * 4;
        p[0] = M;
        p[1] = redl[0] + redl[1] + redl[2] + redl[3];
        p[2] = redy[0] + redy[1] + redy[2] + redy[3];
        p[3] = redx[0] + redx[1] + redx[2] + redx[3];
    }
}

// ---------------- kernel 3: per-batch merge of tile partials ----------------
__global__ __launch_bounds__(256) void reduce_kernel(
    const float* __restrict__ partials, float* __restrict__ out) {
    int b = blockIdx.x;
    int tid = threadIdx.x;
    int wid = tid >> 6, lane = tid & 63;

    float m = -INFINITY, l = 0.f, sy = 0.f, sx = 0.f;
    if (tid < NTILES) {
        const float* p = partials + (size_t)(b * NTILES + tid) * 4;
        m = p[0]; l = p[1]; sy = p[2]; sx = p[3];
    }
    __shared__ float rm[4], rl[4], ry[4], rx[4];
    float mm = m;
    #pragma unroll
    for (int o = 32; o > 0; o >>= 1) mm = fmaxf(mm, __shfl_down(mm, o, 64));
    if (lane == 0) rm[wid] = mm;
    __syncthreads();
    float M = fmaxf(fmaxf(rm[0], rm[1]), fmaxf(rm[2], rm[3]));

    float sc = (m == -INFINITY) ? 0.f : __expf((m - M) * TEMP_INV);
    l *= sc; sy *= sc; sx *= sc;
    #pragma unroll
    for (int o = 32; o > 0; o >>= 1) {
        l  += __shfl_down(l, o, 64);
        sy += __shfl_down(sy, o, 64);
        sx += __shfl_down(sx, o, 64);
    }
    if (lane == 0) { rl[wid] = l; ry[wid] = sy; rx[wid] = sx; }
    __syncthreads();
    if (tid == 0) {
        float L  = rl[0] + rl[1] + rl[2] + rl[3];
        float SY = ry[0] + ry[1] + ry[2] + ry[3];
        float SX = rx[0] + rx[1] + rx[2] + rx[3];
        out[b * 2 + 0] = SX / L - 183.5f;
        out[b * 2 + 1] = SY / L - 183.5f;
        out[2 * NB + b] = M;
    }
}

extern "C" void kernel_launch(void* const* d_in, const int* in_sizes, int n_in,
                              void* d_out, int out_size, void* d_ws, size_t ws_size,
                              hipStream_t stream) {
    const float* piece = (const float*)d_in[0];   // [256,1,17,17]
    const float* bgg   = (const float*)d_in[1];   // [256,1,384,384]
    float* out = (float*)d_out;                   // 512 offsets + 256 max_corr

    float* tn = (float*)d_ws;                     // 256 * 340 floats
    float* partials = tn + NB * HT * TPAD;        // 256*36*4 floats

    tmpl_norm_kernel<<<NB, 256, 0, stream>>>(piece, tn);
    corr_kernel<<<NB * NTILES, 256, 0, stream>>>(bgg, tn, partials);
    reduce_kernel<<<NB, 256, 0, stream>>>(partials, out);
}